// Round 8
// baseline (1265.214 us; speedup 1.0000x reference)
//
#include <hip/hip_runtime.h>
#include <math.h>

#define NN 100000
#define NE 1600000
#define D 128

#define BSZ 128                         // dst-nodes per bucket
#define NB 782                          // ceil(NN/BSZ)
#define CAPB 3072                       // fixed ebuf capacity per bucket (mean 2046, +22 sigma)
#define CHUNK 4096                      // edges per partition block
#define NBLK ((NE + CHUNK - 1) / CHUNK) // 391

#define TILE 2048                       // raw records per pull tile (256/wave)
#define P 8                             // pull register-pipeline depth

#define BM 64            // rows per block in MFMA GEMM
#define LDT 136          // padded LDS row stride for x tile (bf16 units)

#define ASG __attribute__((address_space(1)))
#define ASL __attribute__((address_space(3)))

typedef __attribute__((ext_vector_type(8))) short bf16x8;
typedef __attribute__((ext_vector_type(4))) float f32x4;

__device__ __forceinline__ unsigned short f2bf(float f) {
    unsigned int u = __builtin_bit_cast(unsigned int, f);
    unsigned int r = (u + 0x7FFFu + ((u >> 16) & 1u)) >> 16;   // RTNE
    return (unsigned short)r;
}

// ---------------------------------------------------------------------------
// W precompute: fp32 W -> bf16, stored SLOT-SWIZZLED in global so gemm can
// DMA it linearly into LDS and read fragments conflict-free.
// ---------------------------------------------------------------------------
__global__ __launch_bounds__(256) void wconv_kernel(const float* __restrict__ W,
                                                    unsigned short* __restrict__ Wswz) {
    int i = blockIdx.x * 256 + threadIdx.x;   // 2048 threads total
    int r = i >> 4, s = i & 15;
    const float4* wp = reinterpret_cast<const float4*>(W + (size_t)r * D + s * 8);
    float4 v0 = wp[0], v1 = wp[1];
    ushort4 b0, b1;
    b0.x = f2bf(v0.x); b0.y = f2bf(v0.y); b0.z = f2bf(v0.z); b0.w = f2bf(v0.w);
    b1.x = f2bf(v1.x); b1.y = f2bf(v1.y); b1.z = f2bf(v1.z); b1.w = f2bf(v1.w);
    int so = s ^ (r & 15);
    unsigned short* op = Wswz + (size_t)r * D + so * 8;
    *reinterpret_cast<ushort4*>(op)     = b0;
    *reinterpret_cast<ushort4*>(op + 4) = b1;
}

// ---------------------------------------------------------------------------
// MFMA GEMM: h = bf16(x) @ bf16(W)^T, fp32 accumulate, bf16 output.
// h is written DIM-PERMUTED: dim k stored at position 2*(k&63) + (k>>6), so
// pull's lane l reads ONE dword containing dims (l, l+64).
// ---------------------------------------------------------------------------
__global__ __launch_bounds__(256) void mfma_gemm_kernel(const float* __restrict__ x,
                                                        const unsigned short* __restrict__ Wswz,
                                                        unsigned short* __restrict__ h) {
    __shared__ __align__(16) unsigned short lA[BM * LDT];    // 17408 B
    __shared__ __align__(16) unsigned short lB[128 * 128];   // 32768 B, swizzled content
    const int tid = threadIdx.x;
    const int lane = tid & 63;
    const int w = tid >> 6;
    const int rowBase = blockIdx.x * BM;

    // DMA Wswz -> lB: 32 wave-instrs of 1 KB (8 per wave), linear copy.
#pragma unroll
    for (int q = 0; q < 8; ++q) {
        const unsigned char* gp = reinterpret_cast<const unsigned char*>(Wswz)
                                  + (size_t)((w * 8 + q) * 1024 + lane * 16);
        unsigned char* lp = reinterpret_cast<unsigned char*>(lB) + (w * 8 + q) * 1024;
        __builtin_amdgcn_global_load_lds((ASG const unsigned int*)(const void*)gp,
                                         (ASL unsigned int*)(void*)lp, 16, 0, 0);
    }

    // Stage x tile (64x128 fp32 -> bf16): 8 float4 per thread.
#pragma unroll
    for (int i = 0; i < 8; ++i) {
        int f = tid + 256 * i;
        int r = f >> 5, c4 = f & 31;
        int gr = rowBase + r;
        float4 v = {0.f, 0.f, 0.f, 0.f};
        if (gr < NN) v = *reinterpret_cast<const float4*>(x + (size_t)gr * D + c4 * 4);
        ushort4 b;
        b.x = f2bf(v.x); b.y = f2bf(v.y); b.z = f2bf(v.z); b.w = f2bf(v.w);
        *reinterpret_cast<ushort4*>(&lA[r * LDT + c4 * 4]) = b;
    }
    __syncthreads();   // drains vmcnt (DMA) + lgkm

    const int l16 = lane & 15;
    const int koff = (lane >> 4) * 8;          // bf16 units
    const int kx16 = (lane >> 4) * 16;         // byte offset of slot within row

    f32x4 acc[8];
#pragma unroll
    for (int j = 0; j < 8; ++j) acc[j] = (f32x4){0.f, 0.f, 0.f, 0.f};

    const int arow = w * 16 + l16;
    const int bxor = l16 << 4;
#pragma unroll
    for (int kk = 0; kk < 4; ++kk) {
        int kbase = kk * 32 + koff;
        bf16x8 a = *reinterpret_cast<const bf16x8*>(&lA[arow * LDT + kbase]);
        int kbyte = kk * 64 + kx16;
#pragma unroll
        for (int j = 0; j < 8; ++j) {
            int row = j * 16 + l16;
            bf16x8 b = *reinterpret_cast<const bf16x8*>(
                reinterpret_cast<const unsigned char*>(lB) + row * 256 + (kbyte ^ bxor));
            acc[j] = __builtin_amdgcn_mfma_f32_16x16x32_bf16(a, b, acc[j], 0, 0, 0);
        }
    }

    const int crow0 = rowBase + w * 16 + (lane >> 4) * 4;
#pragma unroll
    for (int j = 0; j < 8; ++j) {
        int col = j * 16 + l16;
        int pcol = 2 * (col & 63) + (col >> 6);   // dim-permuted position
#pragma unroll
        for (int q = 0; q < 4; ++q) {
            int gr = crow0 + q;
            if (gr < NN) h[(size_t)gr * D + pcol] = f2bf(acc[j][q]);
        }
    }
}

// ---------------------------------------------------------------------------
// Multi-split scatter into fixed-capacity bucket regions (unchanged).
// Record: x = src | (dstLocal<<17), y = val. cursor[b] ends as bucket count.
// ---------------------------------------------------------------------------
__global__ __launch_bounds__(256) void scatter_kernel(const int* __restrict__ src,
                                                      const int* __restrict__ dst,
                                                      const float* __restrict__ vals,
                                                      int* __restrict__ bucketCursor,
                                                      uint2* __restrict__ ebuf) {
    __shared__ int l_start[NB];
    __shared__ int l_cur[NB];
    __shared__ int l_gbase[NB];
    __shared__ int l_scan[256];
    __shared__ uint2 s_rec[CHUNK];
    __shared__ int s_gd[CHUNK];

    int t = threadIdx.x;
    int cb = blockIdx.x * CHUNK;
    int nloc = min(CHUNK, NE - cb);

    for (int i = t; i < NB; i += 256) l_cur[i] = 0;
    __syncthreads();
#pragma unroll
    for (int i = 0; i < CHUNK / 256; ++i) {
        int e = cb + t + 256 * i;
        if (e < NE) atomicAdd(&l_cur[dst[e] >> 7], 1);
    }
    __syncthreads();

    int c[4];
    int s = 0;
#pragma unroll
    for (int i = 0; i < 4; ++i) {
        int b = 4 * t + i;
        c[i] = (b < NB) ? l_cur[b] : 0;
        s += c[i];
    }
    l_scan[t] = s;
    __syncthreads();
    for (int off = 1; off < 256; off <<= 1) {
        int v = (t >= off) ? l_scan[t - off] : 0;
        __syncthreads();
        l_scan[t] += v;
        __syncthreads();
    }
    int run = l_scan[t] - s;
#pragma unroll
    for (int i = 0; i < 4; ++i) {
        int b = 4 * t + i;
        if (b < NB) {
            l_start[b] = run;
            l_cur[b]   = run;
            l_gbase[b] = b * CAPB + (c[i] ? atomicAdd(&bucketCursor[b], c[i]) : 0);
        }
        run += c[i];
    }
    __syncthreads();

#pragma unroll
    for (int i = 0; i < CHUNK / 256; ++i) {
        int e = cb + t + 256 * i;
        if (e < NE) {
            int dn = dst[e];
            int b = dn >> 7;
            uint2 rec;
            rec.x = (unsigned int)src[e] | ((unsigned int)(dn & 127) << 17);
            rec.y = __float_as_uint(vals[e]);
            int lofs = atomicAdd(&l_cur[b], 1);
            s_rec[lofs] = rec;
            s_gd[lofs] = l_gbase[b] + (lofs - l_start[b]);
        }
    }
    __syncthreads();

#pragma unroll
    for (int i = 0; i < CHUNK / 256; ++i) {
        int j = t + 256 * i;
        if (j < nloc) ebuf[s_gd[j]] = s_rec[j];
    }
}

// ---------------------------------------------------------------------------
// Pull v3: 2 blocks per bucket (half = 64 nodes). fp32 LDS accumulator with
// ds_add_f32 (2-way bank alias via permuted h = free). Wave-private ballot
// compaction (no sort, no block sync in the loop), P=8 register-pipelined
// h-gathers. Fused GELU epilogue. 48 KB LDS -> 3 blocks/CU.
// ---------------------------------------------------------------------------
__global__ __launch_bounds__(512) void pull_kernel(const unsigned short* __restrict__ h,
                                                   const int* __restrict__ bucketCursor,
                                                   const uint2* __restrict__ ebuf,
                                                   float* __restrict__ out) {
    __shared__ float acc[64 * D];        // 32 KB
    __shared__ uint2 rbuf[TILE];         // 16 KB: 8 waves x 256 private slots

    const int t = threadIdx.x;
    const int lane = t & 63;
    const int w = t >> 6;
    const int bid = blockIdx.x;
    const int b = bid >> 1;
    const int half = bid & 1;
    const int nodeBase = b * BSZ + half * 64;

    float4* a4 = reinterpret_cast<float4*>(acc);
#pragma unroll
    for (int i = 0; i < 4; ++i) a4[t + 512 * i] = (float4){0.f, 0.f, 0.f, 0.f};
    __syncthreads();

    const int n = bucketCursor[b];
    const uint2* eb = ebuf + (size_t)b * CAPB;
    uint2* myrb = rbuf + w * 256;
    const unsigned char* hb = reinterpret_cast<const unsigned char*>(h);

    for (int tb = 0; tb < n; tb += TILE) {
        // ---- wave-private ballot compaction of this wave's 256 raw recs ----
        int cnt = 0;
#pragma unroll
        for (int c = 0; c < 4; ++c) {
            int j = tb + w * 256 + c * 64 + lane;
            uint2 r = (j < n) ? eb[j] : (uint2){0u, 0u};
            int dl = (int)((r.x >> 17) & 127);
            bool own = (j < n) && ((dl >> 6) == half);
            unsigned long long m = __ballot(own);
            if (own) {
                int pos = cnt + (int)__popcll(m & ((1ull << lane) - 1ull));
                myrb[pos] = r;
            }
            cnt += (int)__popcll(m);
        }
        // wave-private region: no block sync needed

        // ---- P-deep register-pipelined consume of myrb[0..cnt) ----
        int dn[P]; float va[P]; unsigned int hv[P];
        int e = 0;
#pragma unroll
        for (int j = 0; j < P; ++j) {
            dn[j] = -1;
            if (e < cnt) {
                uint2 r = myrb[e]; ++e;
                dn[j] = (int)((r.x >> 17) & 63);
                va[j] = __uint_as_float(r.y);
                hv[j] = *reinterpret_cast<const unsigned int*>(
                    hb + (size_t)(r.x & 0x1FFFFu) * 256 + lane * 4);
            }
        }
        while (true) {
            bool did = false;
#pragma unroll
            for (int j = 0; j < P; ++j) {
                if (dn[j] >= 0) {
                    did = true;
                    float lo = __uint_as_float(hv[j] << 16);
                    float hi = __uint_as_float(hv[j] & 0xFFFF0000u);
                    atomicAdd(&acc[dn[j] * D + lane],      va[j] * lo);
                    atomicAdd(&acc[dn[j] * D + 64 + lane], va[j] * hi);
                    dn[j] = -1;
                    if (e < cnt) {
                        uint2 r = myrb[e]; ++e;
                        dn[j] = (int)((r.x >> 17) & 63);
                        va[j] = __uint_as_float(r.y);
                        hv[j] = *reinterpret_cast<const unsigned int*>(
                            hb + (size_t)(r.x & 0x1FFFFu) * 256 + lane * 4);
                    }
                }
            }
            if (!did) break;
        }
    }
    __syncthreads();

    // epilogue: exact GELU + coalesced float4 write
    const float is2 = 0.70710678118654752f;
#pragma unroll
    for (int i = 0; i < 4; ++i) {
        int f = t + 512 * i;                 // float4 index in [0, 2048)
        int node = nodeBase + (f >> 5);
        if (node < NN) {
            float4 v = a4[f];
            v.x = 0.5f * v.x * (1.f + erff(v.x * is2));
            v.y = 0.5f * v.y * (1.f + erff(v.y * is2));
            v.z = 0.5f * v.z * (1.f + erff(v.z * is2));
            v.w = 0.5f * v.w * (1.f + erff(v.w * is2));
            *reinterpret_cast<float4*>(out + (size_t)node * D + (f & 31) * 4) = v;
        }
    }
}

extern "C" void kernel_launch(void* const* d_in, const int* in_sizes, int n_in,
                              void* d_out, int out_size, void* d_ws, size_t ws_size,
                              hipStream_t stream) {
    const float* x    = (const float*)d_in[0];
    const float* W    = (const float*)d_in[1];
    const float* vals = (const float*)d_in[2];
    const int*   src  = (const int*)d_in[3];
    const int*   dst  = (const int*)d_in[4];
    float* out = (float*)d_out;

    // ws: h bf16 (25.6MB) | bucketCursor | Wswz (32KB) | ebuf (NB*CAPB*8 = 19.2MB)
    char* ws = (char*)d_ws;
    size_t off = 0;
    unsigned short* h    = (unsigned short*)(ws + off); off += (size_t)NN * D * 2;
    int* bucketCursor    = (int*)(ws + off);            off += ((size_t)NB + 4) * 4;
    off = (off + 15) & ~(size_t)15;
    unsigned short* Wswz = (unsigned short*)(ws + off); off += (size_t)D * D * 2;
    off = (off + 15) & ~(size_t)15;
    uint2* ebuf          = (uint2*)(ws + off);          off += (size_t)NB * CAPB * 8;

    hipMemsetAsync(bucketCursor, 0, ((size_t)NB + 4) * 4, stream);

    wconv_kernel<<<8, 256, 0, stream>>>(W, Wswz);
    mfma_gemm_kernel<<<(NN + BM - 1) / BM, 256, 0, stream>>>(x, Wswz, h);
    scatter_kernel<<<NBLK, 256, 0, stream>>>(src, dst, vals, bucketCursor, ebuf);
    pull_kernel<<<NB * 2, 512, 0, stream>>>(h, bucketCursor, ebuf, out);
}

// Round 9
// 198.438 us; speedup vs baseline: 6.3759x; 6.3759x over previous
//
#include <hip/hip_runtime.h>
#include <math.h>

#define NN 100000
#define NE 1600000
#define D 128

#define BSZ 128                         // dst-nodes per bucket
#define NB 782                          // ceil(NN/BSZ)
#define CAPB 3072                       // fixed ebuf capacity per bucket (mean 2046, +22 sigma)
#define CHUNK 4096                      // edges per partition block
#define NBLK ((NE + CHUNK - 1) / CHUNK) // 391
#define CAP 2304                        // sorted-records tile per bucket

#define BM 64            // rows per block in MFMA GEMM
#define LDT 136          // padded LDS row stride for x tile (bf16 units)

#define ASG __attribute__((address_space(1)))
#define ASL __attribute__((address_space(3)))

typedef __attribute__((ext_vector_type(8))) short bf16x8;
typedef __attribute__((ext_vector_type(4))) float f32x4;

__device__ __forceinline__ unsigned short f2bf(float f) {
    unsigned int u = __builtin_bit_cast(unsigned int, f);
    unsigned int r = (u + 0x7FFFu + ((u >> 16) & 1u)) >> 16;   // RTNE
    return (unsigned short)r;
}

// ---------------------------------------------------------------------------
// W precompute: fp32 W -> bf16, stored SLOT-SWIZZLED in global so gemm can
// DMA it linearly into LDS and read fragments conflict-free.
// ---------------------------------------------------------------------------
__global__ __launch_bounds__(256) void wconv_kernel(const float* __restrict__ W,
                                                    unsigned short* __restrict__ Wswz) {
    int i = blockIdx.x * 256 + threadIdx.x;   // 2048 threads total
    int r = i >> 4, s = i & 15;
    const float4* wp = reinterpret_cast<const float4*>(W + (size_t)r * D + s * 8);
    float4 v0 = wp[0], v1 = wp[1];
    ushort4 b0, b1;
    b0.x = f2bf(v0.x); b0.y = f2bf(v0.y); b0.z = f2bf(v0.z); b0.w = f2bf(v0.w);
    b1.x = f2bf(v1.x); b1.y = f2bf(v1.y); b1.z = f2bf(v1.z); b1.w = f2bf(v1.w);
    int so = s ^ (r & 15);
    unsigned short* op = Wswz + (size_t)r * D + so * 8;
    *reinterpret_cast<ushort4*>(op)     = b0;
    *reinterpret_cast<ushort4*>(op + 4) = b1;
}

// ---------------------------------------------------------------------------
// MFMA GEMM: h = bf16(x) @ bf16(W)^T, fp32 accumulate, bf16 output.
// W tile arrives by global_load_lds DMA (linear, zero VALU); fragment reads
// un-swizzle with the same XOR. Normal h layout (pull reads dims 2l,2l+1).
// ---------------------------------------------------------------------------
__global__ __launch_bounds__(256) void mfma_gemm_kernel(const float* __restrict__ x,
                                                        const unsigned short* __restrict__ Wswz,
                                                        unsigned short* __restrict__ h) {
    __shared__ __align__(16) unsigned short lA[BM * LDT];    // 17408 B
    __shared__ __align__(16) unsigned short lB[128 * 128];   // 32768 B, swizzled content
    const int tid = threadIdx.x;
    const int lane = tid & 63;
    const int w = tid >> 6;
    const int rowBase = blockIdx.x * BM;

    // DMA Wswz -> lB: 32 wave-instrs of 1 KB (8 per wave), linear copy.
#pragma unroll
    for (int q = 0; q < 8; ++q) {
        const unsigned char* gp = reinterpret_cast<const unsigned char*>(Wswz)
                                  + (size_t)((w * 8 + q) * 1024 + lane * 16);
        unsigned char* lp = reinterpret_cast<unsigned char*>(lB) + (w * 8 + q) * 1024;
        __builtin_amdgcn_global_load_lds((ASG const unsigned int*)(const void*)gp,
                                         (ASL unsigned int*)(void*)lp, 16, 0, 0);
    }

    // Stage x tile (64x128 fp32 -> bf16): 8 float4 per thread.
#pragma unroll
    for (int i = 0; i < 8; ++i) {
        int f = tid + 256 * i;
        int r = f >> 5, c4 = f & 31;
        int gr = rowBase + r;
        float4 v = {0.f, 0.f, 0.f, 0.f};
        if (gr < NN) v = *reinterpret_cast<const float4*>(x + (size_t)gr * D + c4 * 4);
        ushort4 b;
        b.x = f2bf(v.x); b.y = f2bf(v.y); b.z = f2bf(v.z); b.w = f2bf(v.w);
        *reinterpret_cast<ushort4*>(&lA[r * LDT + c4 * 4]) = b;
    }
    __syncthreads();   // drains vmcnt (DMA) + lgkm

    const int l16 = lane & 15;
    const int koff = (lane >> 4) * 8;          // bf16 units
    const int kx16 = (lane >> 4) * 16;         // byte offset of slot within row

    f32x4 acc[8];
#pragma unroll
    for (int j = 0; j < 8; ++j) acc[j] = (f32x4){0.f, 0.f, 0.f, 0.f};

    const int arow = w * 16 + l16;
    const int bxor = l16 << 4;
#pragma unroll
    for (int kk = 0; kk < 4; ++kk) {
        int kbase = kk * 32 + koff;
        bf16x8 a = *reinterpret_cast<const bf16x8*>(&lA[arow * LDT + kbase]);
        int kbyte = kk * 64 + kx16;
#pragma unroll
        for (int j = 0; j < 8; ++j) {
            int row = j * 16 + l16;
            bf16x8 b = *reinterpret_cast<const bf16x8*>(
                reinterpret_cast<const unsigned char*>(lB) + row * 256 + (kbyte ^ bxor));
            acc[j] = __builtin_amdgcn_mfma_f32_16x16x32_bf16(a, b, acc[j], 0, 0, 0);
        }
    }

    const int crow0 = rowBase + w * 16 + (lane >> 4) * 4;
#pragma unroll
    for (int j = 0; j < 8; ++j) {
        int col = j * 16 + l16;
#pragma unroll
        for (int q = 0; q < 4; ++q) {
            int gr = crow0 + q;
            if (gr < NN) h[(size_t)gr * D + col] = f2bf(acc[j][q]);
        }
    }
}

// ---------------------------------------------------------------------------
// Multi-split scatter into fixed-capacity bucket regions (unchanged).
// Record: x = src | (dstLocal<<17), y = val. cursor[b] ends as bucket count.
// ---------------------------------------------------------------------------
__global__ __launch_bounds__(256) void scatter_kernel(const int* __restrict__ src,
                                                      const int* __restrict__ dst,
                                                      const float* __restrict__ vals,
                                                      int* __restrict__ bucketCursor,
                                                      uint2* __restrict__ ebuf) {
    __shared__ int l_start[NB];
    __shared__ int l_cur[NB];
    __shared__ int l_gbase[NB];
    __shared__ int l_scan[256];
    __shared__ uint2 s_rec[CHUNK];
    __shared__ int s_gd[CHUNK];

    int t = threadIdx.x;
    int cb = blockIdx.x * CHUNK;
    int nloc = min(CHUNK, NE - cb);

    for (int i = t; i < NB; i += 256) l_cur[i] = 0;
    __syncthreads();
#pragma unroll
    for (int i = 0; i < CHUNK / 256; ++i) {
        int e = cb + t + 256 * i;
        if (e < NE) atomicAdd(&l_cur[dst[e] >> 7], 1);
    }
    __syncthreads();

    int c[4];
    int s = 0;
#pragma unroll
    for (int i = 0; i < 4; ++i) {
        int b = 4 * t + i;
        c[i] = (b < NB) ? l_cur[b] : 0;
        s += c[i];
    }
    l_scan[t] = s;
    __syncthreads();
    for (int off = 1; off < 256; off <<= 1) {
        int v = (t >= off) ? l_scan[t - off] : 0;
        __syncthreads();
        l_scan[t] += v;
        __syncthreads();
    }
    int run = l_scan[t] - s;
#pragma unroll
    for (int i = 0; i < 4; ++i) {
        int b = 4 * t + i;
        if (b < NB) {
            l_start[b] = run;
            l_cur[b]   = run;
            l_gbase[b] = b * CAPB + (c[i] ? atomicAdd(&bucketCursor[b], c[i]) : 0);
        }
        run += c[i];
    }
    __syncthreads();

#pragma unroll
    for (int i = 0; i < CHUNK / 256; ++i) {
        int e = cb + t + 256 * i;
        if (e < NE) {
            int dn = dst[e];
            int b = dn >> 7;
            uint2 rec;
            rec.x = (unsigned int)src[e] | ((unsigned int)(dn & 127) << 17);
            rec.y = __float_as_uint(vals[e]);
            int lofs = atomicAdd(&l_cur[b], 1);
            s_rec[lofs] = rec;
            s_gd[lofs] = l_gbase[b] + (lofs - l_start[b]);
        }
    }
    __syncthreads();

#pragma unroll
    for (int i = 0; i < CHUNK / 256; ++i) {
        int j = t + 256 * i;
        if (j < nloc) ebuf[s_gd[j]] = s_rec[j];
    }
}

// ---------------------------------------------------------------------------
// Pull (round-6 structure, deeper ring): one block per bucket. Counting sort
// by local dst into srec, then each wave streams its 16 nodes' contiguous
// runs through a 3-slot LDS ring filled by global_load_lds DMA (8 edges x
// 256B per group = 2 instrs), always-issue discipline, counted vmcnt(4) ->
// 2 groups in flight during consume. Register accumulate, fused GELU.
// ---------------------------------------------------------------------------
__global__ __launch_bounds__(512) void pull_kernel(const unsigned short* __restrict__ h,
                                                   const int* __restrict__ bucketCursor,
                                                   const uint2* __restrict__ ebuf,
                                                   float* __restrict__ out) {
    __shared__ uint2 srec[CAP];                              // 18 KB
    __shared__ int cnt[BSZ];
    __shared__ int start[BSZ + 1];
    __shared__ int cur[BSZ];
    __shared__ __align__(16) unsigned char hbuf[8 * 3 * 2048];  // 48 KB: 8 waves x 3 slots x 8 edges x 256 B

    const int t = threadIdx.x;
    const int lane = t & 63;
    const int w = t >> 6;                // 8 waves
    const int b = blockIdx.x;
    const int base = b * BSZ;

    unsigned char* hbufW = hbuf + w * 6144;

    float2 acc[16];
#pragma unroll
    for (int i = 0; i < 16; ++i) acc[i] = (float2){0.f, 0.f};

    const int n = bucketCursor[b];
    const uint2* ebase = ebuf + (size_t)b * CAPB;

    for (int tb = 0; tb < n; tb += CAP) {
        const int nt = min(CAP, n - tb);
        const uint2* eb = ebase + tb;

        if (t < BSZ) cnt[t] = 0;
        __syncthreads();

        // pass 1: histogram of local-dst
        for (int j = t; j < nt; j += 512) {
            unsigned int rx = eb[j].x;
            atomicAdd(&cnt[(rx >> 17) & 127], 1);
        }
        __syncthreads();

        // wave-0 shuffle scan of the 128 counters -> start/cur
        if (w == 0) {
            int c0 = cnt[2 * lane], c1 = cnt[2 * lane + 1];
            int s = c0 + c1;
            for (int off = 1; off < 64; off <<= 1) {
                int v = __shfl_up(s, off);
                if (lane >= off) s += v;
            }
            int excl = s - c0 - c1;
            start[2 * lane] = excl;
            start[2 * lane + 1] = excl + c0;
            cur[2 * lane] = excl;
            cur[2 * lane + 1] = excl + c0;
            if (lane == 63) start[BSZ] = s;
        }
        __syncthreads();

        // pass 2: scatter records into srec sorted by local dst
        for (int j = t; j < nt; j += 512) {
            uint2 rec = eb[j];
            int dl = (rec.x >> 17) & 127;
            int p = atomicAdd(&cur[dl], 1);
            srec[p] = rec;
        }
        __syncthreads();

        // ---- streamed accumulate: wave w owns nodes [w*16, w*16+16) ----
        const int wbeg = start[w * 16];
        const int wend = start[w * 16 + 16];
        int issued = 0;       // 8-edge groups issued (2 DMA instrs each)
        int consumed = 0;

        auto issue_group = [&]() {
            int gbase = wbeg + issued * 8;
#pragma unroll
            for (int q = 0; q < 2; ++q) {
                int idx = min(gbase + q * 4 + (lane >> 4), wend - 1);
                unsigned int rx = reinterpret_cast<const unsigned int*>(&srec[idx])[0];
                const unsigned char* gp = reinterpret_cast<const unsigned char*>(h)
                                          + (size_t)(rx & 0x1FFFFu) * 256 + (size_t)((lane & 15) * 16);
                unsigned char* lp = hbufW + (issued % 3) * 2048 + q * 1024;
                __builtin_amdgcn_global_load_lds((ASG const unsigned int*)(const void*)gp,
                                                 (ASL unsigned int*)(void*)lp, 16, 0, 0);
            }
            issued++;
        };

        if (wend > wbeg) { issue_group(); issue_group(); }

#pragma unroll
        for (int i = 0; i < 16; ++i) {
            const int s1 = start[w * 16 + i + 1];
            float2 a = acc[i];
            for (int e = start[w * 16 + i]; e < s1; ++e) {
                if (e >= wbeg + consumed * 8) {
                    // entering group `consumed`: issue group consumed+2 into
                    // slot (consumed+2)%3 (= slot of consumed-1, drained),
                    // then wait until group `consumed` has landed.
                    issue_group();
                    asm volatile("s_waitcnt vmcnt(4)" ::: "memory");
                    __builtin_amdgcn_sched_barrier(0);
                    consumed++;
                }
                int le = e - wbeg;
                unsigned int hw = *reinterpret_cast<const unsigned int*>(
                    hbufW + ((le >> 3) % 3) * 2048 + (le & 7) * 256 + lane * 4);
                float v = __uint_as_float(reinterpret_cast<const unsigned int*>(&srec[e])[1]);
                a.x = fmaf(v, __uint_as_float(hw << 16), a.x);
                a.y = fmaf(v, __uint_as_float(hw & 0xFFFF0000u), a.y);
            }
            acc[i] = a;
        }
        __syncthreads();   // drains dangling DMA; srec reused next tile
    }

    // epilogue: exact GELU + coalesced write
    const float is2 = 0.70710678118654752f;
#pragma unroll
    for (int i = 0; i < 16; ++i) {
        int node = base + w * 16 + i;
        if (node < NN) {
            float a0 = acc[i].x, a1 = acc[i].y;
            a0 = 0.5f * a0 * (1.f + erff(a0 * is2));
            a1 = 0.5f * a1 * (1.f + erff(a1 * is2));
            float2 o; o.x = a0; o.y = a1;
            *reinterpret_cast<float2*>(out + (size_t)node * D + lane * 2) = o;
        }
    }
}

extern "C" void kernel_launch(void* const* d_in, const int* in_sizes, int n_in,
                              void* d_out, int out_size, void* d_ws, size_t ws_size,
                              hipStream_t stream) {
    const float* x    = (const float*)d_in[0];
    const float* W    = (const float*)d_in[1];
    const float* vals = (const float*)d_in[2];
    const int*   src  = (const int*)d_in[3];
    const int*   dst  = (const int*)d_in[4];
    float* out = (float*)d_out;

    // ws: h bf16 (25.6MB) | bucketCursor | Wswz (32KB) | ebuf (NB*CAPB*8 = 19.2MB)
    char* ws = (char*)d_ws;
    size_t off = 0;
    unsigned short* h    = (unsigned short*)(ws + off); off += (size_t)NN * D * 2;
    int* bucketCursor    = (int*)(ws + off);            off += ((size_t)NB + 4) * 4;
    off = (off + 15) & ~(size_t)15;
    unsigned short* Wswz = (unsigned short*)(ws + off); off += (size_t)D * D * 2;
    off = (off + 15) & ~(size_t)15;
    uint2* ebuf          = (uint2*)(ws + off);          off += (size_t)NB * CAPB * 8;

    hipMemsetAsync(bucketCursor, 0, ((size_t)NB + 4) * 4, stream);

    wconv_kernel<<<8, 256, 0, stream>>>(W, Wswz);
    mfma_gemm_kernel<<<(NN + BM - 1) / BM, 256, 0, stream>>>(x, Wswz, h);
    scatter_kernel<<<NBLK, 256, 0, stream>>>(src, dst, vals, bucketCursor, ebuf);
    pull_kernel<<<NB, 512, 0, stream>>>(h, bucketCursor, ebuf, out);
}

// Round 10
// 184.087 us; speedup vs baseline: 6.8729x; 1.0780x over previous
//
#include <hip/hip_runtime.h>
#include <math.h>

#define NN 100000
#define NE 1600000
#define D 128

#define BSZ 64                          // dst-nodes per bucket
#define NB 1563                         // ceil(NN/BSZ)
#define CAPB 1280                       // fixed ebuf capacity per bucket (mean 1024, +8 sigma)
#define CHUNK 4096                      // edges per partition block
#define NBLK ((NE + CHUNK - 1) / CHUNK) // 391
#define CAP 1280                        // sorted-records tile per bucket (== CAPB)

#define BM 64            // rows per block in MFMA GEMM
#define LDT 136          // padded LDS row stride for x tile (bf16 units)

#define ASG __attribute__((address_space(1)))
#define ASL __attribute__((address_space(3)))

typedef __attribute__((ext_vector_type(8))) short bf16x8;
typedef __attribute__((ext_vector_type(4))) float f32x4;

__device__ __forceinline__ unsigned short f2bf(float f) {
    unsigned int u = __builtin_bit_cast(unsigned int, f);
    unsigned int r = (u + 0x7FFFu + ((u >> 16) & 1u)) >> 16;   // RTNE
    return (unsigned short)r;
}

// ---------------------------------------------------------------------------
// W precompute: fp32 W -> bf16, stored SLOT-SWIZZLED in global so gemm can
// DMA it linearly into LDS and read fragments conflict-free.
// ---------------------------------------------------------------------------
__global__ __launch_bounds__(256) void wconv_kernel(const float* __restrict__ W,
                                                    unsigned short* __restrict__ Wswz) {
    int i = blockIdx.x * 256 + threadIdx.x;   // 2048 threads total
    int r = i >> 4, s = i & 15;
    const float4* wp = reinterpret_cast<const float4*>(W + (size_t)r * D + s * 8);
    float4 v0 = wp[0], v1 = wp[1];
    ushort4 b0, b1;
    b0.x = f2bf(v0.x); b0.y = f2bf(v0.y); b0.z = f2bf(v0.z); b0.w = f2bf(v0.w);
    b1.x = f2bf(v1.x); b1.y = f2bf(v1.y); b1.z = f2bf(v1.z); b1.w = f2bf(v1.w);
    int so = s ^ (r & 15);
    unsigned short* op = Wswz + (size_t)r * D + so * 8;
    *reinterpret_cast<ushort4*>(op)     = b0;
    *reinterpret_cast<ushort4*>(op + 4) = b1;
}

// ---------------------------------------------------------------------------
// MFMA GEMM: h = bf16(x) @ bf16(W)^T, fp32 accumulate, bf16 output.
// W tile arrives by global_load_lds DMA; fragment reads un-swizzle with the
// same XOR. Normal h layout (pull reads dims 2l,2l+1 as one dword).
// ---------------------------------------------------------------------------
__global__ __launch_bounds__(256) void mfma_gemm_kernel(const float* __restrict__ x,
                                                        const unsigned short* __restrict__ Wswz,
                                                        unsigned short* __restrict__ h) {
    __shared__ __align__(16) unsigned short lA[BM * LDT];    // 17408 B
    __shared__ __align__(16) unsigned short lB[128 * 128];   // 32768 B, swizzled content
    const int tid = threadIdx.x;
    const int lane = tid & 63;
    const int w = tid >> 6;
    const int rowBase = blockIdx.x * BM;

#pragma unroll
    for (int q = 0; q < 8; ++q) {
        const unsigned char* gp = reinterpret_cast<const unsigned char*>(Wswz)
                                  + (size_t)((w * 8 + q) * 1024 + lane * 16);
        unsigned char* lp = reinterpret_cast<unsigned char*>(lB) + (w * 8 + q) * 1024;
        __builtin_amdgcn_global_load_lds((ASG const unsigned int*)(const void*)gp,
                                         (ASL unsigned int*)(void*)lp, 16, 0, 0);
    }

#pragma unroll
    for (int i = 0; i < 8; ++i) {
        int f = tid + 256 * i;
        int r = f >> 5, c4 = f & 31;
        int gr = rowBase + r;
        float4 v = {0.f, 0.f, 0.f, 0.f};
        if (gr < NN) v = *reinterpret_cast<const float4*>(x + (size_t)gr * D + c4 * 4);
        ushort4 b;
        b.x = f2bf(v.x); b.y = f2bf(v.y); b.z = f2bf(v.z); b.w = f2bf(v.w);
        *reinterpret_cast<ushort4*>(&lA[r * LDT + c4 * 4]) = b;
    }
    __syncthreads();   // drains vmcnt (DMA) + lgkm

    const int l16 = lane & 15;
    const int koff = (lane >> 4) * 8;
    const int kx16 = (lane >> 4) * 16;

    f32x4 acc[8];
#pragma unroll
    for (int j = 0; j < 8; ++j) acc[j] = (f32x4){0.f, 0.f, 0.f, 0.f};

    const int arow = w * 16 + l16;
    const int bxor = l16 << 4;
#pragma unroll
    for (int kk = 0; kk < 4; ++kk) {
        int kbase = kk * 32 + koff;
        bf16x8 a = *reinterpret_cast<const bf16x8*>(&lA[arow * LDT + kbase]);
        int kbyte = kk * 64 + kx16;
#pragma unroll
        for (int j = 0; j < 8; ++j) {
            int row = j * 16 + l16;
            bf16x8 b = *reinterpret_cast<const bf16x8*>(
                reinterpret_cast<const unsigned char*>(lB) + row * 256 + (kbyte ^ bxor));
            acc[j] = __builtin_amdgcn_mfma_f32_16x16x32_bf16(a, b, acc[j], 0, 0, 0);
        }
    }

    const int crow0 = rowBase + w * 16 + (lane >> 4) * 4;
#pragma unroll
    for (int j = 0; j < 8; ++j) {
        int col = j * 16 + l16;
#pragma unroll
        for (int q = 0; q < 4; ++q) {
            int gr = crow0 + q;
            if (gr < NN) h[(size_t)gr * D + col] = f2bf(acc[j][q]);
        }
    }
}

// ---------------------------------------------------------------------------
// Multi-split scatter into fixed-capacity 64-node bucket regions.
// Record: x = src | (dstLocal<<17) [6 bits], y = val. cursor[b] -> count.
// ---------------------------------------------------------------------------
__global__ __launch_bounds__(256) void scatter_kernel(const int* __restrict__ src,
                                                      const int* __restrict__ dst,
                                                      const float* __restrict__ vals,
                                                      int* __restrict__ bucketCursor,
                                                      uint2* __restrict__ ebuf) {
    __shared__ int l_start[NB];
    __shared__ int l_cur[NB];
    __shared__ int l_gbase[NB];
    __shared__ int l_scan[256];
    __shared__ uint2 s_rec[CHUNK];
    __shared__ int s_gd[CHUNK];

    int t = threadIdx.x;
    int cb = blockIdx.x * CHUNK;
    int nloc = min(CHUNK, NE - cb);

    for (int i = t; i < NB; i += 256) l_cur[i] = 0;
    __syncthreads();

    int dreg[CHUNK / 256];
#pragma unroll
    for (int i = 0; i < CHUNK / 256; ++i) {
        int e = cb + t + 256 * i;
        dreg[i] = (e < NE) ? dst[e] : -1;
        if (dreg[i] >= 0) atomicAdd(&l_cur[dreg[i] >> 6], 1);
    }
    __syncthreads();

    int c[7];
    int s = 0;
#pragma unroll
    for (int i = 0; i < 7; ++i) {
        int b = 7 * t + i;
        c[i] = (b < NB) ? l_cur[b] : 0;
        s += c[i];
    }
    l_scan[t] = s;
    __syncthreads();
    for (int off = 1; off < 256; off <<= 1) {
        int v = (t >= off) ? l_scan[t - off] : 0;
        __syncthreads();
        l_scan[t] += v;
        __syncthreads();
    }
    int run = l_scan[t] - s;
#pragma unroll
    for (int i = 0; i < 7; ++i) {
        int b = 7 * t + i;
        if (b < NB) {
            l_start[b] = run;
            l_cur[b]   = run;
            l_gbase[b] = b * CAPB + (c[i] ? atomicAdd(&bucketCursor[b], c[i]) : 0);
        }
        run += c[i];
    }
    __syncthreads();

#pragma unroll
    for (int i = 0; i < CHUNK / 256; ++i) {
        int e = cb + t + 256 * i;
        if (dreg[i] >= 0) {
            int dn = dreg[i];
            int b = dn >> 6;
            uint2 rec;
            rec.x = (unsigned int)src[e] | ((unsigned int)(dn & 63) << 17);
            rec.y = __float_as_uint(vals[e]);
            int lofs = atomicAdd(&l_cur[b], 1);
            s_rec[lofs] = rec;
            s_gd[lofs] = l_gbase[b] + (lofs - l_start[b]);
        }
    }
    __syncthreads();

#pragma unroll
    for (int i = 0; i < CHUNK / 256; ++i) {
        int j = t + 256 * i;
        if (j < nloc) ebuf[s_gd[j]] = s_rec[j];
    }
}

// ---------------------------------------------------------------------------
// Pull: one block per 64-node bucket. Counting sort (64 bins, one lane each)
// into srec, then each wave streams its 8 nodes' contiguous runs through the
// r6-proven 2-slot x 8-edge DMA ring (vmcnt(2), issue-at-entry). Register
// accumulate, fused exact GELU. ~44 KB LDS -> 3 blocks/CU.
// ---------------------------------------------------------------------------
__global__ __launch_bounds__(512) void pull_kernel(const unsigned short* __restrict__ h,
                                                   const int* __restrict__ bucketCursor,
                                                   const uint2* __restrict__ ebuf,
                                                   float* __restrict__ out) {
    __shared__ uint2 srec[CAP];                              // 10240 B
    __shared__ int cnt[BSZ];
    __shared__ int start[BSZ + 1];
    __shared__ int cur[BSZ];
    __shared__ __align__(16) unsigned char hbuf[8 * 4096];   // 32 KB: 8 waves x 2 slots x 8 edges x 256 B

    const int t = threadIdx.x;
    const int lane = t & 63;
    const int w = t >> 6;                // 8 waves
    const int b = blockIdx.x;
    const int base = b * BSZ;

    unsigned char* hbufW = hbuf + w * 4096;

    float2 acc[8];
#pragma unroll
    for (int i = 0; i < 8; ++i) acc[i] = (float2){0.f, 0.f};

    const int n = min(bucketCursor[b], CAPB);
    const uint2* eb = ebuf + (size_t)b * CAPB;

    if (t < BSZ) cnt[t] = 0;
    __syncthreads();

    // pass 1: histogram of local-dst (64 bins)
    for (int j = t; j < n; j += 512) {
        unsigned int rx = eb[j].x;
        atomicAdd(&cnt[(rx >> 17) & 63], 1);
    }
    __syncthreads();

    // wave-0: one lane per bin shuffle scan
    if (w == 0) {
        int c = cnt[lane];
        int s = c;
        for (int off = 1; off < 64; off <<= 1) {
            int v = __shfl_up(s, off);
            if (lane >= off) s += v;
        }
        start[lane] = s - c;
        cur[lane] = s - c;
        if (lane == 63) start[BSZ] = s;
    }
    __syncthreads();

    // pass 2: scatter records into srec sorted by local dst
    for (int j = t; j < n; j += 512) {
        uint2 rec = eb[j];
        int dl = (rec.x >> 17) & 63;
        int p = atomicAdd(&cur[dl], 1);
        srec[p] = rec;
    }
    __syncthreads();

    // ---- streamed accumulate: wave w owns nodes [w*8, w*8+8) ----
    const int wbeg = start[w * 8];
    const int wend = start[w * 8 + 8];
    int issued = 0;       // 8-edge groups issued (2 DMA instrs each)
    int consumed = 0;

    auto issue_group = [&]() {
        int gbase = wbeg + issued * 8;
#pragma unroll
        for (int q = 0; q < 2; ++q) {
            int idx = min(gbase + q * 4 + (lane >> 4), wend - 1);
            unsigned int rx = reinterpret_cast<const unsigned int*>(&srec[idx])[0];
            const unsigned char* gp = reinterpret_cast<const unsigned char*>(h)
                                      + (size_t)(rx & 0x1FFFFu) * 256 + (size_t)((lane & 15) * 16);
            unsigned char* lp = hbufW + (issued & 1) * 2048 + q * 1024;
            __builtin_amdgcn_global_load_lds((ASG const unsigned int*)(const void*)gp,
                                             (ASL unsigned int*)(void*)lp, 16, 0, 0);
        }
        issued++;
    };

    if (wend > wbeg) { issue_group(); issue_group(); }

#pragma unroll
    for (int i = 0; i < 8; ++i) {
        const int s1 = start[w * 8 + i + 1];
        float2 a = acc[i];
        for (int e = start[w * 8 + i]; e < s1; ++e) {
            if (e >= wbeg + consumed * 8) {
                if (consumed) issue_group();
                asm volatile("s_waitcnt vmcnt(2)" ::: "memory");
                __builtin_amdgcn_sched_barrier(0);
                consumed++;
            }
            int le = e - wbeg;
            unsigned int hw = *reinterpret_cast<const unsigned int*>(
                hbufW + ((le >> 3) & 1) * 2048 + (le & 7) * 256 + lane * 4);
            float v = __uint_as_float(reinterpret_cast<const unsigned int*>(&srec[e])[1]);
            a.x = fmaf(v, __uint_as_float(hw << 16), a.x);
            a.y = fmaf(v, __uint_as_float(hw & 0xFFFF0000u), a.y);
        }
        acc[i] = a;
    }
    __syncthreads();   // drains dangling DMA

    // epilogue: exact GELU + coalesced write
    const float is2 = 0.70710678118654752f;
#pragma unroll
    for (int i = 0; i < 8; ++i) {
        int node = base + w * 8 + i;
        if (node < NN) {
            float a0 = acc[i].x, a1 = acc[i].y;
            a0 = 0.5f * a0 * (1.f + erff(a0 * is2));
            a1 = 0.5f * a1 * (1.f + erff(a1 * is2));
            float2 o; o.x = a0; o.y = a1;
            *reinterpret_cast<float2*>(out + (size_t)node * D + lane * 2) = o;
        }
    }
}

extern "C" void kernel_launch(void* const* d_in, const int* in_sizes, int n_in,
                              void* d_out, int out_size, void* d_ws, size_t ws_size,
                              hipStream_t stream) {
    const float* x    = (const float*)d_in[0];
    const float* W    = (const float*)d_in[1];
    const float* vals = (const float*)d_in[2];
    const int*   src  = (const int*)d_in[3];
    const int*   dst  = (const int*)d_in[4];
    float* out = (float*)d_out;

    // ws: h bf16 (25.6MB) | bucketCursor | Wswz (32KB) | ebuf (NB*CAPB*8 = 16MB)
    char* ws = (char*)d_ws;
    size_t off = 0;
    unsigned short* h    = (unsigned short*)(ws + off); off += (size_t)NN * D * 2;
    int* bucketCursor    = (int*)(ws + off);            off += ((size_t)NB + 4) * 4;
    off = (off + 15) & ~(size_t)15;
    unsigned short* Wswz = (unsigned short*)(ws + off); off += (size_t)D * D * 2;
    off = (off + 15) & ~(size_t)15;
    uint2* ebuf          = (uint2*)(ws + off);          off += (size_t)NB * CAPB * 8;

    hipMemsetAsync(bucketCursor, 0, ((size_t)NB + 4) * 4, stream);

    wconv_kernel<<<8, 256, 0, stream>>>(W, Wswz);
    mfma_gemm_kernel<<<(NN + BM - 1) / BM, 256, 0, stream>>>(x, Wswz, h);
    scatter_kernel<<<NBLK, 256, 0, stream>>>(src, dst, vals, bucketCursor, ebuf);
    pull_kernel<<<NB, 512, 0, stream>>>(h, bucketCursor, ebuf, out);
}

// Round 11
// 169.792 us; speedup vs baseline: 7.4515x; 1.0842x over previous
//
#include <hip/hip_runtime.h>
#include <math.h>

#define NN 100000
#define NE 1600000
#define D 128

#define NB 782                          // buckets of 128 dst-nodes (scatter granularity)
#define CAPB 2560                       // fixed ebuf capacity per bucket (mean 2046, +11 sigma)
#define SC_BLOCKS 512                   // scatter grid: exactly 2 blocks/CU, zero tail
#define SC_CHUNK 3125                   // 512 x 3125 = 1.6M exactly
#define SC_IT 13                        // ceil(3125/256)
#define CAP 1408                        // pull sorted tile (half-bucket mean 1023, +12 sigma)

#define BM 64            // rows per block in MFMA GEMM
#define LDT 136          // padded LDS row stride for x tile (bf16 units)
#define TPAD 264         // transpose-epilogue row stride in bytes (8-bank shift / 4 rows)

#define ASG __attribute__((address_space(1)))
#define ASL __attribute__((address_space(3)))

typedef __attribute__((ext_vector_type(8))) short bf16x8;
typedef __attribute__((ext_vector_type(4))) float f32x4;

__device__ __forceinline__ unsigned short f2bf(float f) {
    unsigned int u = __builtin_bit_cast(unsigned int, f);
    unsigned int r = (u + 0x7FFFu + ((u >> 16) & 1u)) >> 16;   // RTNE
    return (unsigned short)r;
}

__device__ __forceinline__ unsigned int cvt_pk_bf16(float lo, float hi) {
    unsigned int r;
    asm("v_cvt_pk_bf16_f32 %0, %1, %2" : "=v"(r) : "v"(lo), "v"(hi));
    return r;
}

// ---------------------------------------------------------------------------
// W precompute: fp32 W -> bf16, SLOT-SWIZZLED in global for gemm's linear DMA.
// ---------------------------------------------------------------------------
__global__ __launch_bounds__(256) void wconv_kernel(const float* __restrict__ W,
                                                    unsigned short* __restrict__ Wswz) {
    int i = blockIdx.x * 256 + threadIdx.x;   // 2048 threads total
    int r = i >> 4, s = i & 15;
    const float4* wp = reinterpret_cast<const float4*>(W + (size_t)r * D + s * 8);
    float4 v0 = wp[0], v1 = wp[1];
    uint2 a, b;
    a.x = cvt_pk_bf16(v0.x, v0.y); a.y = cvt_pk_bf16(v0.z, v0.w);
    b.x = cvt_pk_bf16(v1.x, v1.y); b.y = cvt_pk_bf16(v1.z, v1.w);
    int so = s ^ (r & 15);
    unsigned short* op = Wswz + (size_t)r * D + so * 8;
    *reinterpret_cast<uint2*>(op)     = a;
    *reinterpret_cast<uint2*>(op + 4) = b;
}

// ---------------------------------------------------------------------------
// MFMA GEMM: h = bf16(x) @ bf16(W)^T. cvt_pk staging; LDS-transpose epilogue
// with coalesced dwordx2 h-stores.
// ---------------------------------------------------------------------------
__global__ __launch_bounds__(256) void mfma_gemm_kernel(const float* __restrict__ x,
                                                        const unsigned short* __restrict__ Wswz,
                                                        unsigned short* __restrict__ h) {
    __shared__ __align__(16) unsigned char lAbuf[BM * LDT * 2];   // 17408 B (stage + transpose)
    __shared__ __align__(16) unsigned short lB[128 * 128];        // 32768 B, swizzled content
    unsigned short* lA = reinterpret_cast<unsigned short*>(lAbuf);
    const int tid = threadIdx.x;
    const int lane = tid & 63;
    const int w = tid >> 6;
    const int rowBase = blockIdx.x * BM;

    // DMA Wswz -> lB (linear, zero VALU)
#pragma unroll
    for (int q = 0; q < 8; ++q) {
        const unsigned char* gp = reinterpret_cast<const unsigned char*>(Wswz)
                                  + (size_t)((w * 8 + q) * 1024 + lane * 16);
        unsigned char* lp = reinterpret_cast<unsigned char*>(lB) + (w * 8 + q) * 1024;
        __builtin_amdgcn_global_load_lds((ASG const unsigned int*)(const void*)gp,
                                         (ASL unsigned int*)(void*)lp, 16, 0, 0);
    }

    // Stage x tile (64x128 fp32 -> bf16 via cvt_pk): 8 float4 per thread.
#pragma unroll
    for (int i = 0; i < 8; ++i) {
        int f = tid + 256 * i;
        int r = f >> 5, c4 = f & 31;
        int gr = rowBase + r;
        float4 v = {0.f, 0.f, 0.f, 0.f};
        if (gr < NN) v = *reinterpret_cast<const float4*>(x + (size_t)gr * D + c4 * 4);
        uint2 p;
        p.x = cvt_pk_bf16(v.x, v.y);
        p.y = cvt_pk_bf16(v.z, v.w);
        *reinterpret_cast<uint2*>(&lA[r * LDT + c4 * 4]) = p;
    }
    __syncthreads();   // drains vmcnt (DMA) + lgkm

    const int l16 = lane & 15;
    const int koff = (lane >> 4) * 8;
    const int kx16 = (lane >> 4) * 16;

    f32x4 acc[8];
#pragma unroll
    for (int j = 0; j < 8; ++j) acc[j] = (f32x4){0.f, 0.f, 0.f, 0.f};

    const int arow = w * 16 + l16;
    const int bxor = l16 << 4;
#pragma unroll
    for (int kk = 0; kk < 4; ++kk) {
        int kbase = kk * 32 + koff;
        bf16x8 a = *reinterpret_cast<const bf16x8*>(&lA[arow * LDT + kbase]);
        int kbyte = kk * 64 + kx16;
#pragma unroll
        for (int j = 0; j < 8; ++j) {
            int row = j * 16 + l16;
            bf16x8 b = *reinterpret_cast<const bf16x8*>(
                reinterpret_cast<const unsigned char*>(lB) + row * 256 + (kbyte ^ bxor));
            acc[j] = __builtin_amdgcn_mfma_f32_16x16x32_bf16(a, b, acc[j], 0, 0, 0);
        }
    }
    __syncthreads();   // all waves done reading lA -> reuse as transpose buffer

    // Transpose epilogue: write bf16 elements row-major into lT (stride TPAD).
    const int lrBase = w * 16 + (lane >> 4) * 4;
#pragma unroll
    for (int j = 0; j < 8; ++j) {
        int col = j * 16 + l16;
        unsigned int d01 = cvt_pk_bf16(acc[j][0], acc[j][1]);
        unsigned int d23 = cvt_pk_bf16(acc[j][2], acc[j][3]);
        unsigned char* p0 = lAbuf + (lrBase + 0) * TPAD + col * 2;
        *reinterpret_cast<unsigned short*>(p0)              = (unsigned short)d01;
        *reinterpret_cast<unsigned short*>(p0 + TPAD)       = (unsigned short)(d01 >> 16);
        *reinterpret_cast<unsigned short*>(p0 + 2 * TPAD)   = (unsigned short)d23;
        *reinterpret_cast<unsigned short*>(p0 + 3 * TPAD)   = (unsigned short)(d23 >> 16);
    }
    __syncthreads();

    // Coalesced store-out: 8B chunks, 64 rows x 32 chunks.
#pragma unroll
    for (int i = 0; i < 8; ++i) {
        int f = tid + 256 * i;
        int r = f >> 5, c = f & 31;
        if (rowBase + r < NN) {
            uint2 v = *reinterpret_cast<const uint2*>(lAbuf + r * TPAD + c * 8);
            *reinterpret_cast<uint2*>(reinterpret_cast<unsigned char*>(h)
                                      + (size_t)(rowBase + r) * 256 + c * 8) = v;
        }
    }
}

// ---------------------------------------------------------------------------
// Multi-split scatter: 512 balanced blocks x 3125 edges, 782 buckets of 128.
// Record: x = src | (dstLocal<<17) [7 bits], y = val. cursor[b] -> count.
// ---------------------------------------------------------------------------
__global__ __launch_bounds__(256) void scatter_kernel(const int* __restrict__ src,
                                                      const int* __restrict__ dst,
                                                      const float* __restrict__ vals,
                                                      int* __restrict__ bucketCursor,
                                                      uint2* __restrict__ ebuf) {
    __shared__ int l_off[NB];            // gbase - run_start  (flush: gd = l_off[b]+slot)
    __shared__ int l_cur[NB];
    __shared__ int l_cnt[NB];
    __shared__ int wtot[4];
    __shared__ uint2 s_rec[SC_CHUNK];            // 25000 B
    __shared__ unsigned short s_b[SC_CHUNK];     // 6250 B

    const int t = threadIdx.x;
    const int lane = t & 63;
    const int w = t >> 6;
    const int cb = blockIdx.x * SC_CHUNK;

    for (int i = t; i < NB; i += 256) l_cnt[i] = 0;
    __syncthreads();

    int dreg[SC_IT];
#pragma unroll
    for (int i = 0; i < SC_IT; ++i) {
        int o = t + 256 * i;
        dreg[i] = (o < SC_CHUNK) ? dst[cb + o] : -1;
        if (dreg[i] >= 0) atomicAdd(&l_cnt[dreg[i] >> 7], 1);
    }
    __syncthreads();

    // scan of 782 bins: 4 bins/thread, wave shfl scan + 4-wave combine
    int c[4];
    int s = 0;
#pragma unroll
    for (int i = 0; i < 4; ++i) {
        int b = 4 * t + i;
        c[i] = (b < NB) ? l_cnt[b] : 0;
        s += c[i];
    }
    int incl = s;
#pragma unroll
    for (int off = 1; off < 64; off <<= 1) {
        int v = __shfl_up(incl, off);
        if (lane >= off) incl += v;
    }
    if (lane == 63) wtot[w] = incl;
    __syncthreads();
    int run = incl - s;
    for (int k = 0; k < 4; ++k) if (k < w) run += wtot[k];
#pragma unroll
    for (int i = 0; i < 4; ++i) {
        int b = 4 * t + i;
        if (b < NB) {
            l_cur[b] = run;
            int gbase = b * CAPB + (c[i] ? atomicAdd(&bucketCursor[b], c[i]) : 0);
            l_off[b] = gbase - run;
        }
        run += c[i];
    }
    __syncthreads();

    // reorder into LDS by bucket
#pragma unroll
    for (int i = 0; i < SC_IT; ++i) {
        int o = t + 256 * i;
        if (dreg[i] >= 0) {
            int dn = dreg[i];
            int b = dn >> 7;
            uint2 rec;
            rec.x = (unsigned int)src[cb + o] | ((unsigned int)(dn & 127) << 17);
            rec.y = __float_as_uint(vals[cb + o]);
            int lofs = atomicAdd(&l_cur[b], 1);
            s_rec[lofs] = rec;
            s_b[lofs] = (unsigned short)b;
        }
    }
    __syncthreads();

    // flush: contiguous per-bucket runs
#pragma unroll
    for (int i = 0; i < SC_IT; ++i) {
        int j = t + 256 * i;
        if (j < SC_CHUNK) {
            int b = s_b[j];
            ebuf[l_off[b] + j] = s_rec[j];
        }
    }
}

// ---------------------------------------------------------------------------
// Pull: 2 blocks per 128-bucket; each filters its 64-node half on read,
// counting-sorts into srec (64 bins), then streams contiguous runs through
// the 2-slot x 8-edge DMA ring (vmcnt(2)). Pointer-walking consume.
// ---------------------------------------------------------------------------
__global__ __launch_bounds__(512) void pull_kernel(const unsigned short* __restrict__ h,
                                                   const int* __restrict__ bucketCursor,
                                                   const uint2* __restrict__ ebuf,
                                                   float* __restrict__ out) {
    __shared__ uint2 srec[CAP];                              // 11264 B
    __shared__ int cnt[64];
    __shared__ int start[65];
    __shared__ int cur[64];
    __shared__ __align__(16) unsigned char hbuf[8 * 4096];   // 32 KB

    const int t = threadIdx.x;
    const int lane = t & 63;
    const int w = t >> 6;                // 8 waves
    const int bid = blockIdx.x;
    const int b = bid >> 1;
    const int half = bid & 1;
    const int nodeBase = b * 128 + half * 64;

    unsigned char* hbufW = hbuf + w * 4096;

    float2 acc[8];
#pragma unroll
    for (int i = 0; i < 8; ++i) acc[i] = (float2){0.f, 0.f};

    const int n = min(bucketCursor[b], CAPB);
    const uint2* eb = ebuf + (size_t)b * CAPB;

    if (t < 64) cnt[t] = 0;
    __syncthreads();

    // pass 1: histogram of own-half local-dst
    for (int j = t; j < n; j += 512) {
        unsigned int rx = eb[j].x;
        int dl = (int)((rx >> 17) & 127);
        if ((dl >> 6) == half) atomicAdd(&cnt[dl & 63], 1);
    }
    __syncthreads();

    if (w == 0) {
        int c = cnt[lane];
        int s = c;
        for (int off = 1; off < 64; off <<= 1) {
            int v = __shfl_up(s, off);
            if (lane >= off) s += v;
        }
        start[lane] = s - c;
        cur[lane] = s - c;
        if (lane == 63) start[64] = s;
    }
    __syncthreads();

    // pass 2: scatter own records into srec sorted by local dst
    for (int j = t; j < n; j += 512) {
        uint2 rec = eb[j];
        int dl = (int)((rec.x >> 17) & 127);
        if ((dl >> 6) == half) {
            int p = atomicAdd(&cur[dl & 63], 1);
            srec[p] = rec;
        }
    }
    __syncthreads();

    // ---- streamed accumulate: wave w owns nodes [w*8, w*8+8) ----
    const int wbeg = start[w * 8];
    const int wend = start[w * 8 + 8];
    int issued = 0;
    int consumed = 0;

    auto issue_group = [&]() {
        int gbase = wbeg + issued * 8;
#pragma unroll
        for (int q = 0; q < 2; ++q) {
            int idx = min(gbase + q * 4 + (lane >> 4), wend - 1);
            unsigned int rx = reinterpret_cast<const unsigned int*>(&srec[idx])[0];
            const unsigned char* gp = reinterpret_cast<const unsigned char*>(h)
                                      + (size_t)(rx & 0x1FFFFu) * 256 + (size_t)((lane & 15) * 16);
            unsigned char* lp = hbufW + (issued & 1) * 2048 + q * 1024;
            __builtin_amdgcn_global_load_lds((ASG const unsigned int*)(const void*)gp,
                                             (ASL unsigned int*)(void*)lp, 16, 0, 0);
        }
        issued++;
    };

    if (wend > wbeg) { issue_group(); issue_group(); }

    int gate = wbeg;
    const unsigned char* hp = hbufW + lane * 4;
    const unsigned char* vp = reinterpret_cast<const unsigned char*>(srec) + (size_t)wbeg * 8 + 4;

#pragma unroll
    for (int i = 0; i < 8; ++i) {
        const int s1 = start[w * 8 + i + 1];
        float2 a = acc[i];
        for (int e = start[w * 8 + i]; e < s1; ++e) {
            if (e >= gate) {
                if (consumed) issue_group();
                asm volatile("s_waitcnt vmcnt(2)" ::: "memory");
                __builtin_amdgcn_sched_barrier(0);
                hp = hbufW + (consumed & 1) * 2048 + lane * 4;
                consumed++;
                gate += 8;
            }
            unsigned int hw = *reinterpret_cast<const unsigned int*>(hp);
            float v = *reinterpret_cast<const float*>(vp);
            hp += 256;
            vp += 8;
            a.x = fmaf(v, __uint_as_float(hw << 16), a.x);
            a.y = fmaf(v, __uint_as_float(hw & 0xFFFF0000u), a.y);
        }
        acc[i] = a;
    }
    __syncthreads();   // drains dangling DMA

    // epilogue: exact GELU + coalesced write
    const float is2 = 0.70710678118654752f;
#pragma unroll
    for (int i = 0; i < 8; ++i) {
        int node = nodeBase + w * 8 + i;
        if (node < NN) {
            float a0 = acc[i].x, a1 = acc[i].y;
            a0 = 0.5f * a0 * (1.f + erff(a0 * is2));
            a1 = 0.5f * a1 * (1.f + erff(a1 * is2));
            float2 o; o.x = a0; o.y = a1;
            *reinterpret_cast<float2*>(out + (size_t)node * D + lane * 2) = o;
        }
    }
}

extern "C" void kernel_launch(void* const* d_in, const int* in_sizes, int n_in,
                              void* d_out, int out_size, void* d_ws, size_t ws_size,
                              hipStream_t stream) {
    const float* x    = (const float*)d_in[0];
    const float* W    = (const float*)d_in[1];
    const float* vals = (const float*)d_in[2];
    const int*   src  = (const int*)d_in[3];
    const int*   dst  = (const int*)d_in[4];
    float* out = (float*)d_out;

    // ws: h bf16 (25.6MB) | bucketCursor | Wswz (32KB) | ebuf (NB*CAPB*8 = 16MB)
    char* ws = (char*)d_ws;
    size_t off = 0;
    unsigned short* h    = (unsigned short*)(ws + off); off += (size_t)NN * D * 2;
    int* bucketCursor    = (int*)(ws + off);            off += ((size_t)NB + 4) * 4;
    off = (off + 15) & ~(size_t)15;
    unsigned short* Wswz = (unsigned short*)(ws + off); off += (size_t)D * D * 2;
    off = (off + 15) & ~(size_t)15;
    uint2* ebuf          = (uint2*)(ws + off);          off += (size_t)NB * CAPB * 8;

    hipMemsetAsync(bucketCursor, 0, ((size_t)NB + 4) * 4, stream);

    wconv_kernel<<<8, 256, 0, stream>>>(W, Wswz);
    mfma_gemm_kernel<<<(NN + BM - 1) / BM, 256, 0, stream>>>(x, Wswz, h);
    scatter_kernel<<<SC_BLOCKS, 256, 0, stream>>>(src, dst, vals, bucketCursor, ebuf);
    pull_kernel<<<NB * 2, 512, 0, stream>>>(h, bucketCursor, ebuf, out);
}

// Round 12
// 150.399 us; speedup vs baseline: 8.4124x; 1.1289x over previous
//
#include <hip/hip_runtime.h>
#include <math.h>

#define NN 100000
#define NE 1600000
#define D 128

#define NB 782                          // buckets of 128 dst-nodes (scatter granularity)
#define CAPB 2560                       // fixed ebuf capacity per bucket (mean 2046, +11 sigma)
#define SC_BLOCKS 512                   // scatter role: exactly 2 blocks/CU-worth, zero tail
#define SC_CHUNK 3125                   // 512 x 3125 = 1.6M exactly
#define SC_IT 13                        // ceil(3125/256)
#define CAP 1408                        // pull sorted tile (half-bucket mean 1023, +12 sigma)
#define GM_BLOCKS 1563                  // ceil(NN/BM)

#define BM 64            // rows per block in MFMA GEMM
#define LDT 136          // padded LDS row stride for x tile (bf16 units)
#define TPAD 264         // transpose-epilogue row stride in bytes

#define ASG __attribute__((address_space(1)))
#define ASL __attribute__((address_space(3)))

typedef __attribute__((ext_vector_type(8))) short bf16x8;
typedef __attribute__((ext_vector_type(4))) float f32x4;

__device__ __forceinline__ unsigned int cvt_pk_bf16(float lo, float hi) {
    unsigned int r;
    asm("v_cvt_pk_bf16_f32 %0, %1, %2" : "=v"(r) : "v"(lo), "v"(hi));
    return r;
}

// ---------------------------------------------------------------------------
// W precompute (fp32 -> bf16, slot-swizzled) + bucketCursor zeroing (block 7).
// ---------------------------------------------------------------------------
__global__ __launch_bounds__(256) void wconv_kernel(const float* __restrict__ W,
                                                    unsigned short* __restrict__ Wswz,
                                                    int* __restrict__ bucketCursor) {
    int i = blockIdx.x * 256 + threadIdx.x;   // 2048 threads total
    int r = i >> 4, s = i & 15;
    const float4* wp = reinterpret_cast<const float4*>(W + (size_t)r * D + s * 8);
    float4 v0 = wp[0], v1 = wp[1];
    uint2 a, b;
    a.x = cvt_pk_bf16(v0.x, v0.y); a.y = cvt_pk_bf16(v0.z, v0.w);
    b.x = cvt_pk_bf16(v1.x, v1.y); b.y = cvt_pk_bf16(v1.z, v1.w);
    int so = s ^ (r & 15);
    unsigned short* op = Wswz + (size_t)r * D + so * 8;
    *reinterpret_cast<uint2*>(op)     = a;
    *reinterpret_cast<uint2*>(op + 4) = b;
    // zero the 786 cursor ints with blocks 0-3 (786 <= 4*256)
    int z = blockIdx.x * 256 + threadIdx.x;
    if (z < NB + 4) bucketCursor[z] = 0;
}

// ---------------------------------------------------------------------------
// FUSED gemm + scatter. Blocks [0, SC_BLOCKS) run the multi-split scatter;
// blocks [SC_BLOCKS, SC_BLOCKS+GM_BLOCKS) run the MFMA GEMM. The two roles
// touch disjoint inputs/outputs and overlap on the CU (MFMA pipe vs LDS/
// atomic pipe). LDS is a 50 KB union of the two layouts.
// ---------------------------------------------------------------------------
__global__ __launch_bounds__(256) void gemm_scatter_kernel(const float* __restrict__ x,
                                                           const unsigned short* __restrict__ Wswz,
                                                           unsigned short* __restrict__ h,
                                                           const int* __restrict__ src,
                                                           const int* __restrict__ dst,
                                                           const float* __restrict__ vals,
                                                           int* __restrict__ bucketCursor,
                                                           uint2* __restrict__ ebuf) {
    __shared__ __align__(16) unsigned char smem[50176];
    const int tid = threadIdx.x;
    const int lane = tid & 63;
    const int w = tid >> 6;

    if (blockIdx.x < SC_BLOCKS) {
        // ================= SCATTER role =================
        uint2* s_rec          = reinterpret_cast<uint2*>(smem);               // 25000 B
        int*   l_off          = reinterpret_cast<int*>(smem + 25000);         // 3128 B
        int*   l_cur          = reinterpret_cast<int*>(smem + 28128);         // 3128 B
        int*   l_cnt          = reinterpret_cast<int*>(smem + 31256);         // 3128 B
        int*   wtot           = reinterpret_cast<int*>(smem + 34384);         // 16 B
        unsigned short* s_b   = reinterpret_cast<unsigned short*>(smem + 34400); // 6250 B

        const int t = tid;
        const int cb = blockIdx.x * SC_CHUNK;

        for (int i = t; i < NB; i += 256) l_cnt[i] = 0;
        __syncthreads();

        int dreg[SC_IT];
#pragma unroll
        for (int i = 0; i < SC_IT; ++i) {
            int o = t + 256 * i;
            dreg[i] = (o < SC_CHUNK) ? dst[cb + o] : -1;
            if (dreg[i] >= 0) atomicAdd(&l_cnt[dreg[i] >> 7], 1);
        }
        __syncthreads();

        int c[4];
        int s = 0;
#pragma unroll
        for (int i = 0; i < 4; ++i) {
            int b = 4 * t + i;
            c[i] = (b < NB) ? l_cnt[b] : 0;
            s += c[i];
        }
        int incl = s;
#pragma unroll
        for (int off = 1; off < 64; off <<= 1) {
            int v = __shfl_up(incl, off);
            if (lane >= off) incl += v;
        }
        if (lane == 63) wtot[w] = incl;
        __syncthreads();
        int run = incl - s;
        for (int k = 0; k < 4; ++k) if (k < w) run += wtot[k];
#pragma unroll
        for (int i = 0; i < 4; ++i) {
            int b = 4 * t + i;
            if (b < NB) {
                l_cur[b] = run;
                int gbase = b * CAPB + (c[i] ? atomicAdd(&bucketCursor[b], c[i]) : 0);
                l_off[b] = gbase - run;
            }
            run += c[i];
        }
        __syncthreads();

#pragma unroll
        for (int i = 0; i < SC_IT; ++i) {
            int o = t + 256 * i;
            if (dreg[i] >= 0) {
                int dn = dreg[i];
                int b = dn >> 7;
                uint2 rec;
                rec.x = (unsigned int)src[cb + o] | ((unsigned int)(dn & 127) << 17);
                rec.y = __float_as_uint(vals[cb + o]);
                int lofs = atomicAdd(&l_cur[b], 1);
                s_rec[lofs] = rec;
                s_b[lofs] = (unsigned short)b;
            }
        }
        __syncthreads();

#pragma unroll
        for (int i = 0; i < SC_IT; ++i) {
            int j = t + 256 * i;
            if (j < SC_CHUNK) {
                int b = s_b[j];
                ebuf[l_off[b] + j] = s_rec[j];
            }
        }
    } else {
        // ================= GEMM role =================
        unsigned char* lAbuf = smem;                                          // 17408 B
        unsigned short* lA = reinterpret_cast<unsigned short*>(lAbuf);
        unsigned short* lB = reinterpret_cast<unsigned short*>(smem + 17408); // 32768 B
        const int rowBase = (blockIdx.x - SC_BLOCKS) * BM;

#pragma unroll
        for (int q = 0; q < 8; ++q) {
            const unsigned char* gp = reinterpret_cast<const unsigned char*>(Wswz)
                                      + (size_t)((w * 8 + q) * 1024 + lane * 16);
            unsigned char* lp = reinterpret_cast<unsigned char*>(lB) + (w * 8 + q) * 1024;
            __builtin_amdgcn_global_load_lds((ASG const unsigned int*)(const void*)gp,
                                             (ASL unsigned int*)(void*)lp, 16, 0, 0);
        }

#pragma unroll
        for (int i = 0; i < 8; ++i) {
            int f = tid + 256 * i;
            int r = f >> 5, c4 = f & 31;
            int gr = rowBase + r;
            float4 v = {0.f, 0.f, 0.f, 0.f};
            if (gr < NN) v = *reinterpret_cast<const float4*>(x + (size_t)gr * D + c4 * 4);
            uint2 p;
            p.x = cvt_pk_bf16(v.x, v.y);
            p.y = cvt_pk_bf16(v.z, v.w);
            *reinterpret_cast<uint2*>(&lA[r * LDT + c4 * 4]) = p;
        }
        __syncthreads();   // drains vmcnt (DMA) + lgkm

        const int l16 = lane & 15;
        const int koff = (lane >> 4) * 8;
        const int kx16 = (lane >> 4) * 16;

        f32x4 acc[8];
#pragma unroll
        for (int j = 0; j < 8; ++j) acc[j] = (f32x4){0.f, 0.f, 0.f, 0.f};

        const int arow = w * 16 + l16;
        const int bxor = l16 << 4;
#pragma unroll
        for (int kk = 0; kk < 4; ++kk) {
            int kbase = kk * 32 + koff;
            bf16x8 a = *reinterpret_cast<const bf16x8*>(&lA[arow * LDT + kbase]);
            int kbyte = kk * 64 + kx16;
#pragma unroll
            for (int j = 0; j < 8; ++j) {
                int row = j * 16 + l16;
                bf16x8 b = *reinterpret_cast<const bf16x8*>(
                    reinterpret_cast<const unsigned char*>(lB) + row * 256 + (kbyte ^ bxor));
                acc[j] = __builtin_amdgcn_mfma_f32_16x16x32_bf16(a, b, acc[j], 0, 0, 0);
            }
        }
        __syncthreads();   // all waves done reading lA -> reuse as transpose buffer

        const int lrBase = w * 16 + (lane >> 4) * 4;
#pragma unroll
        for (int j = 0; j < 8; ++j) {
            int col = j * 16 + l16;
            unsigned int d01 = cvt_pk_bf16(acc[j][0], acc[j][1]);
            unsigned int d23 = cvt_pk_bf16(acc[j][2], acc[j][3]);
            unsigned char* p0 = lAbuf + (lrBase + 0) * TPAD + col * 2;
            *reinterpret_cast<unsigned short*>(p0)            = (unsigned short)d01;
            *reinterpret_cast<unsigned short*>(p0 + TPAD)     = (unsigned short)(d01 >> 16);
            *reinterpret_cast<unsigned short*>(p0 + 2 * TPAD) = (unsigned short)d23;
            *reinterpret_cast<unsigned short*>(p0 + 3 * TPAD) = (unsigned short)(d23 >> 16);
        }
        __syncthreads();

#pragma unroll
        for (int i = 0; i < 8; ++i) {
            int f = tid + 256 * i;
            int r = f >> 5, c = f & 31;
            if (rowBase + r < NN) {
                uint2 v = *reinterpret_cast<const uint2*>(lAbuf + r * TPAD + c * 8);
                *reinterpret_cast<uint2*>(reinterpret_cast<unsigned char*>(h)
                                          + (size_t)(rowBase + r) * 256 + c * 8) = v;
            }
        }
    }
}

// ---------------------------------------------------------------------------
// Pull: 2 blocks per 128-bucket; each filters its 64-node half (records
// cached in registers across the two sort passes), counting-sorts into srec,
// then streams contiguous runs through the 2-slot x 8-edge DMA ring
// (vmcnt(2)). Pointer-walking consume, fused exact GELU.
// ---------------------------------------------------------------------------
__global__ __launch_bounds__(512) void pull_kernel(const unsigned short* __restrict__ h,
                                                   const int* __restrict__ bucketCursor,
                                                   const uint2* __restrict__ ebuf,
                                                   float* __restrict__ out) {
    __shared__ uint2 srec[CAP];                              // 11264 B
    __shared__ int cnt[64];
    __shared__ int start[65];
    __shared__ int cur[64];
    __shared__ __align__(16) unsigned char hbuf[8 * 4096];   // 32 KB

    const int t = threadIdx.x;
    const int lane = t & 63;
    const int w = t >> 6;                // 8 waves
    const int bid = blockIdx.x;
    const int b = bid >> 1;
    const int half = bid & 1;
    const int nodeBase = b * 128 + half * 64;

    unsigned char* hbufW = hbuf + w * 4096;

    float2 acc[8];
#pragma unroll
    for (int i = 0; i < 8; ++i) acc[i] = (float2){0.f, 0.f};

    const int n = min(bucketCursor[b], CAPB);
    const uint2* eb = ebuf + (size_t)b * CAPB;

    if (t < 64) cnt[t] = 0;
    __syncthreads();

    // pass 1: read records ONCE into registers; histogram own-half local-dst
    uint2 rcache[5];
#pragma unroll
    for (int it = 0; it < 5; ++it) {
        int j = t + 512 * it;
        uint2 r = (j < n) ? eb[j] : (uint2){0xFFFFFFFFu, 0u};
        rcache[it] = r;
        if (j < n) {
            int dl = (int)((r.x >> 17) & 127);
            if ((dl >> 6) == half) atomicAdd(&cnt[dl & 63], 1);
        }
    }
    __syncthreads();

    if (w == 0) {
        int c = cnt[lane];
        int s = c;
        for (int off = 1; off < 64; off <<= 1) {
            int v = __shfl_up(s, off);
            if (lane >= off) s += v;
        }
        start[lane] = s - c;
        cur[lane] = s - c;
        if (lane == 63) start[64] = s;
    }
    __syncthreads();

    // pass 2: scatter own cached records into srec sorted by local dst
#pragma unroll
    for (int it = 0; it < 5; ++it) {
        int j = t + 512 * it;
        if (j < n) {
            uint2 rec = rcache[it];
            int dl = (int)((rec.x >> 17) & 127);
            if ((dl >> 6) == half) {
                int p = atomicAdd(&cur[dl & 63], 1);
                srec[p] = rec;
            }
        }
    }
    __syncthreads();

    // ---- streamed accumulate: wave w owns nodes [w*8, w*8+8) ----
    const int wbeg = start[w * 8];
    const int wend = start[w * 8 + 8];
    int issued = 0;
    int consumed = 0;

    auto issue_group = [&]() {
        int gbase = wbeg + issued * 8;
#pragma unroll
        for (int q = 0; q < 2; ++q) {
            int idx = min(gbase + q * 4 + (lane >> 4), wend - 1);
            unsigned int rx = reinterpret_cast<const unsigned int*>(&srec[idx])[0];
            const unsigned char* gp = reinterpret_cast<const unsigned char*>(h)
                                      + (size_t)(rx & 0x1FFFFu) * 256 + (size_t)((lane & 15) * 16);
            unsigned char* lp = hbufW + (issued & 1) * 2048 + q * 1024;
            __builtin_amdgcn_global_load_lds((ASG const unsigned int*)(const void*)gp,
                                             (ASL unsigned int*)(void*)lp, 16, 0, 0);
        }
        issued++;
    };

    if (wend > wbeg) { issue_group(); issue_group(); }

    int gate = wbeg;
    const unsigned char* hp = hbufW + lane * 4;
    const unsigned char* vp = reinterpret_cast<const unsigned char*>(srec) + (size_t)wbeg * 8 + 4;

#pragma unroll
    for (int i = 0; i < 8; ++i) {
        const int s1 = start[w * 8 + i + 1];
        float2 a = acc[i];
        for (int e = start[w * 8 + i]; e < s1; ++e) {
            if (e >= gate) {
                if (consumed) issue_group();
                asm volatile("s_waitcnt vmcnt(2)" ::: "memory");
                __builtin_amdgcn_sched_barrier(0);
                hp = hbufW + (consumed & 1) * 2048 + lane * 4;
                consumed++;
                gate += 8;
            }
            unsigned int hw = *reinterpret_cast<const unsigned int*>(hp);
            float v = *reinterpret_cast<const float*>(vp);
            hp += 256;
            vp += 8;
            a.x = fmaf(v, __uint_as_float(hw << 16), a.x);
            a.y = fmaf(v, __uint_as_float(hw & 0xFFFF0000u), a.y);
        }
        acc[i] = a;
    }
    __syncthreads();   // drains dangling DMA

    // epilogue: exact GELU + coalesced write
    const float is2 = 0.70710678118654752f;
#pragma unroll
    for (int i = 0; i < 8; ++i) {
        int node = nodeBase + w * 8 + i;
        if (node < NN) {
            float a0 = acc[i].x, a1 = acc[i].y;
            a0 = 0.5f * a0 * (1.f + erff(a0 * is2));
            a1 = 0.5f * a1 * (1.f + erff(a1 * is2));
            float2 o; o.x = a0; o.y = a1;
            *reinterpret_cast<float2*>(out + (size_t)node * D + lane * 2) = o;
        }
    }
}

extern "C" void kernel_launch(void* const* d_in, const int* in_sizes, int n_in,
                              void* d_out, int out_size, void* d_ws, size_t ws_size,
                              hipStream_t stream) {
    const float* x    = (const float*)d_in[0];
    const float* W    = (const float*)d_in[1];
    const float* vals = (const float*)d_in[2];
    const int*   src  = (const int*)d_in[3];
    const int*   dst  = (const int*)d_in[4];
    float* out = (float*)d_out;

    // ws: h bf16 (25.6MB) | bucketCursor | Wswz (32KB) | ebuf (NB*CAPB*8 = 16MB)
    char* ws = (char*)d_ws;
    size_t off = 0;
    unsigned short* h    = (unsigned short*)(ws + off); off += (size_t)NN * D * 2;
    int* bucketCursor    = (int*)(ws + off);            off += ((size_t)NB + 4) * 4;
    off = (off + 15) & ~(size_t)15;
    unsigned short* Wswz = (unsigned short*)(ws + off); off += (size_t)D * D * 2;
    off = (off + 15) & ~(size_t)15;
    uint2* ebuf          = (uint2*)(ws + off);          off += (size_t)NB * CAPB * 8;

    wconv_kernel<<<8, 256, 0, stream>>>(W, Wswz, bucketCursor);
    gemm_scatter_kernel<<<SC_BLOCKS + GM_BLOCKS, 256, 0, stream>>>(
        x, Wswz, h, src, dst, vals, bucketCursor, ebuf);
    pull_kernel<<<NB * 2, 512, 0, stream>>>(h, bucketCursor, ebuf, out);
}